// Round 9
// baseline (892.036 us; speedup 1.0000x reference)
//
#include <hip/hip_runtime.h>
#include <math.h>

#define NN 100000
#define EE 800000
static constexpr size_t N128 = (size_t)NN * 128;

__device__ __forceinline__ float lrelu(float x) { return x >= 0.f ? x : 0.2f * x; }

// ---------------- init: zero degree counters ----------------
__global__ void k_init(int* __restrict__ deg) {
    int i = blockIdx.x * blockDim.x + threadIdx.x;
    if (i < NN) deg[i] = 0;
}

// ---------------- histogram of dst (edge_index arrives as int32) ----------------
__global__ void k_hist(const int* __restrict__ ei, int* __restrict__ deg) {
    int e = blockIdx.x * blockDim.x + threadIdx.x;
    if (e < EE) {
        int dst = ei[EE + e];
        atomicAdd(&deg[dst], 1);
    }
}

// ---------------- scan pass A: per-block sums ----------------
__global__ void k_scanA(const int* __restrict__ deg, int* __restrict__ bsum) {
    int b = blockIdx.x, t = threadIdx.x;
    int i = b * 256 + t;
    int v = (i < NN) ? deg[i] : 0;
    #pragma unroll
    for (int d = 1; d < 64; d <<= 1) v += __shfl_xor(v, d);
    __shared__ int ws[4];
    int lane = t & 63, w = t >> 6;
    if (lane == 0) ws[w] = v;
    __syncthreads();
    if (t == 0) bsum[b] = ws[0] + ws[1] + ws[2] + ws[3];
}

// ---------------- scan pass B: exclusive scan of block sums (1 wave) ----------------
__global__ void k_scanB(int* __restrict__ bsum, int* __restrict__ rowptr, int nb) {
    int lane = threadIdx.x;
    int carry = 0;
    for (int base = 0; base < nb; base += 64) {
        int i = base + lane;
        int v = (i < nb) ? bsum[i] : 0;
        int incl = v;
        #pragma unroll
        for (int d = 1; d < 64; d <<= 1) {
            int u = __shfl_up(incl, d);
            if (lane >= d) incl += u;
        }
        if (i < nb) bsum[i] = carry + incl - v;  // exclusive offset
        carry += __shfl(incl, 63);
    }
    if (lane == 0) rowptr[NN] = carry;  // == EE
}

// ---------------- scan pass C: in-block exclusive scan -> rowptr, cursor ----------------
__global__ void k_scanC(int* __restrict__ deg_and_cur, int* __restrict__ rowptr,
                        const int* __restrict__ bsum) {
    int b = blockIdx.x, t = threadIdx.x;
    int i = b * 256 + t;
    int lane = t & 63, w = t >> 6;
    int v = (i < NN) ? deg_and_cur[i] : 0;
    int incl = v;
    #pragma unroll
    for (int d = 1; d < 64; d <<= 1) {
        int u = __shfl_up(incl, d);
        if (lane >= d) incl += u;
    }
    __shared__ int wtot[4];
    if (lane == 63) wtot[w] = incl;
    __syncthreads();
    int woff = 0;
    for (int k = 0; k < w; k++) woff += wtot[k];
    int excl = woff + incl - v + bsum[b];
    if (i < NN) {
        rowptr[i] = excl;
        deg_and_cur[i] = excl;  // cursor copy for scatter
    }
}

// ---------------- scatter edges into CSR (store src only) ----------------
__global__ void k_scat(const int* __restrict__ ei, int* __restrict__ cur,
                       int* __restrict__ esrc) {
    int e = blockIdx.x * blockDim.x + threadIdx.x;
    if (e < EE) {
        int src = ei[e];
        int dst = ei[EE + e];
        int pos = atomicAdd(&cur[dst], 1);
        esrc[pos] = src;
    }
}

// ---------------- per-layer transform GEMM: xl, xr ----------------
// o_m[n][c] = sum_k x[n][k] * W_m[c][k] + b_m[c]
// v2 (R8 counters: VALUBusy 37%, Occ 19%, LDS 52KB -> latency-bound):
// x tile removed from LDS. The a-operand read is same-address across the 16
// tx lanes (broadcast) so L1 serves it; only W stays in LDS (18.4 KB/block)
// -> LDS-allowed occupancy rises ~3x, staging writes + their bank conflicts gone.
__global__ __launch_bounds__(256) void k_gemm2(
    const float* __restrict__ x,
    const float* __restrict__ W0, const float* __restrict__ B0,
    const float* __restrict__ W1, const float* __restrict__ B1,
    float* __restrict__ o0, float* __restrict__ o1) {
    __shared__ float4 wsm[128][9];
    const float* Ws[2] = {W0, W1};
    const float* Bs[2] = {B0, B1};
    float* Os[2] = {o0, o1};

    int tid = threadIdx.x;
    int row0 = blockIdx.x * 64;
    int ty = tid >> 4, tx = tid & 15;

    // per-thread row indices (clamped for safe loads; stores stay guarded)
    int grow[4], gclamp[4];
    #pragma unroll
    for (int i = 0; i < 4; i++) {
        grow[i] = row0 + ty + 16 * i;
        gclamp[i] = grow[i] < NN ? grow[i] : NN - 1;
    }
    const float4* x4 = (const float4*)x;

    for (int m = 0; m < 2; m++) {
        float acc[4][8];
        #pragma unroll
        for (int i = 0; i < 4; i++)
            #pragma unroll
            for (int j = 0; j < 8; j++) acc[i][j] = 0.f;

        for (int kc = 0; kc < 4; kc++) {
            __syncthreads();  // protect wsm from previous chunk's readers
            #pragma unroll
            for (int q = 0; q < 4; q++) {
                int idx = q * 256 + tid;
                int r = idx >> 3, c4 = idx & 7;
                wsm[r][c4] = ((const float4*)Ws[m])[r * 32 + kc * 8 + c4];
            }
            __syncthreads();
            #pragma unroll
            for (int kk = 0; kk < 8; kk++) {
                float4 a[4], b[8];
                #pragma unroll
                for (int i = 0; i < 4; i++)
                    a[i] = x4[(size_t)gclamp[i] * 32 + kc * 8 + kk];
                #pragma unroll
                for (int j = 0; j < 8; j++) b[j] = wsm[tx + 16 * j][kk];
                #pragma unroll
                for (int i = 0; i < 4; i++)
                    #pragma unroll
                    for (int j = 0; j < 8; j++) {
                        acc[i][j] += a[i].x * b[j].x;
                        acc[i][j] += a[i].y * b[j].y;
                        acc[i][j] += a[i].z * b[j].z;
                        acc[i][j] += a[i].w * b[j].w;
                    }
            }
        }
        const float* bias = Bs[m];
        float* out = Os[m];
        #pragma unroll
        for (int i = 0; i < 4; i++) {
            if (grow[i] < NN) {
                #pragma unroll
                for (int j = 0; j < 8; j++) {
                    int c = tx + 16 * j;
                    out[(size_t)grow[i] * 128 + c] = acc[i][j] + bias[c];
                }
            }
        }
    }
}

// ---------------- edge phase (one layer): one wave per destination node ----------------
// ACC=0: g[dst] = h + bias      ACC=1: g[dst] += h + bias
template <int ACC>
__global__ __launch_bounds__(256) void k_edge1(
    const float* __restrict__ xl, const float* __restrict__ xr,
    const int* __restrict__ rowptr, const int* __restrict__ esrc,
    const float* __restrict__ att, const float* __restrict__ bias,
    float* __restrict__ g) {
    int wid = (blockIdx.x * blockDim.x + threadIdx.x) >> 6;
    if (wid >= NN) return;
    int lane = threadIdx.x & 63;
    int c0 = 2 * lane;         // global channel of .x
    int h = lane >> 4;         // head
    int ch = c0 & 31;          // in-head channel

    float2 xrv = *(const float2*)(xr + (size_t)wid * 128 + c0);
    float2 a = *(const float2*)(att + h * 32 + ch);

    int beg = rowptr[wid], end = rowptr[wid + 1];
    float s = 0.f, acc0 = 0.f, acc1 = 0.f;

    for (int e = beg; e < end; ++e) {
        int src = esrc[e];  // uniform across wave (broadcast)
        float2 v = *(const float2*)(xl + (size_t)src * 128 + c0);
        float t = lrelu(v.x + xrv.x) * a.x + lrelu(v.y + xrv.y) * a.y;
        // 16-lane (per-head) sum
        #pragma unroll
        for (int d = 1; d < 16; d <<= 1) t += __shfl_xor(t, d);
        // softmax without max-subtraction: logits are O(+-10), exp is safe,
        // and the max cancels mathematically in ex/sum(ex)
        float ex = __expf(t);
        s += ex;
        acc0 += ex * v.x;
        acc1 += ex * v.y;
    }
    float r = s > 0.f ? 1.f / (s + 1e-16f) : 0.f;
    float2 gv;
    gv.x = acc0 * r + bias[c0];
    gv.y = acc1 * r + bias[c0 + 1];
    float2* gp = (float2*)(g + (size_t)wid * 128 + c0);
    if (ACC) {
        float2 old = *gp;
        gv.x += old.x;
        gv.y += old.y;
    }
    *gp = gv;
}

// ---------------- final projection: out = [g128 | temb(nt)] @ Wc.T + bc ----------------
// temb computed on the fly; g128 lives in d_out and is overwritten (row-disjoint per block)
__global__ __launch_bounds__(256) void k_final(
    const float* __restrict__ g128, const float* __restrict__ nt,
    const float* __restrict__ Wt, const float* __restrict__ bt,
    const float* __restrict__ Wc, const float* __restrict__ bc,
    float* __restrict__ out) {
    __shared__ float4 gs[64][41];   // 40 float4 = 160 floats per row
    __shared__ float4 wc[128][9];
    int tid = threadIdx.x;
    int row0 = blockIdx.x * 64;
    #pragma unroll
    for (int q = 0; q < 8; q++) {
        int idx = q * 256 + tid;
        int r = idx >> 5, c4 = idx & 31;
        int gr = row0 + r;
        float4 v = {0.f, 0.f, 0.f, 0.f};
        if (gr < NN) v = ((const float4*)g128)[(size_t)gr * 32 + c4];
        gs[r][c4] = v;
    }
    // type-embedding part: 64 rows x 8 float4 (32 channels), computed on the fly
    #pragma unroll
    for (int q = 0; q < 2; q++) {
        int idx = q * 256 + tid;
        int r = idx >> 3, c4 = idx & 7;
        int gr = row0 + r;
        float4 v = {0.f, 0.f, 0.f, 0.f};
        if (gr < NN) {
            float n0 = nt[2 * gr], n1 = nt[2 * gr + 1];
            #pragma unroll
            for (int u = 0; u < 4; u++) {
                int c = c4 * 4 + u;
                ((float*)&v)[u] = n0 * Wt[2 * c] + n1 * Wt[2 * c + 1] + bt[c];
            }
        }
        gs[r][32 + c4] = v;
    }
    int ty = tid >> 4, tx = tid & 15;
    float acc[4][8];
    #pragma unroll
    for (int i = 0; i < 4; i++)
        #pragma unroll
        for (int j = 0; j < 8; j++) acc[i][j] = 0.f;

    for (int kc = 0; kc < 5; kc++) {
        __syncthreads();
        #pragma unroll
        for (int q = 0; q < 4; q++) {
            int idx = q * 256 + tid;
            int r = idx >> 3, c4 = idx & 7;
            wc[r][c4] = ((const float4*)Wc)[r * 40 + kc * 8 + c4];
        }
        __syncthreads();
        #pragma unroll
        for (int kk = 0; kk < 8; kk++) {
            float4 a[4], b[8];
            #pragma unroll
            for (int i = 0; i < 4; i++) a[i] = gs[ty + 16 * i][kc * 8 + kk];
            #pragma unroll
            for (int j = 0; j < 8; j++) b[j] = wc[tx + 16 * j][kk];
            #pragma unroll
            for (int i = 0; i < 4; i++)
                #pragma unroll
                for (int j = 0; j < 8; j++) {
                    acc[i][j] += a[i].x * b[j].x;
                    acc[i][j] += a[i].y * b[j].y;
                    acc[i][j] += a[i].z * b[j].z;
                    acc[i][j] += a[i].w * b[j].w;
                }
        }
    }
    #pragma unroll
    for (int i = 0; i < 4; i++) {
        int gr = row0 + ty + 16 * i;
        if (gr < NN) {
            #pragma unroll
            for (int j = 0; j < 8; j++) {
                int c = tx + 16 * j;
                out[(size_t)gr * 128 + c] = acc[i][j] + bc[c];
            }
        }
    }
}

extern "C" void kernel_launch(void* const* d_in, const int* in_sizes, int n_in,
                              void* d_out, int out_size, void* d_ws, size_t ws_size,
                              hipStream_t stream) {
    const float* x = (const float*)d_in[0];
    const int* ei = (const int*)d_in[1];    // harness converts int64 -> int32
    const float* nt = (const float*)d_in[2];
    const float* Wl1 = (const float*)d_in[3];
    const float* bl1 = (const float*)d_in[4];
    const float* Wr1 = (const float*)d_in[5];
    const float* br1 = (const float*)d_in[6];
    const float* att1 = (const float*)d_in[7];
    const float* bias1 = (const float*)d_in[8];
    const float* Wl2 = (const float*)d_in[9];
    const float* bl2 = (const float*)d_in[10];
    const float* Wr2 = (const float*)d_in[11];
    const float* br2 = (const float*)d_in[12];
    const float* att2 = (const float*)d_in[13];
    const float* bias2 = (const float*)d_in[14];
    const float* Wt = (const float*)d_in[15];
    const float* bt = (const float*)d_in[16];
    const float* Wc = (const float*)d_in[17];
    const float* bc = (const float*)d_in[18];
    float* out = (float*)d_out;

    // workspace layout (~107 MB): xl, xr (reused across the two layer passes) + CSR ints.
    // The accumulated g128 = h1+h2 lives in d_out.
    float* ws_f = (float*)d_ws;
    float* xl = ws_f;
    float* xr = ws_f + N128;
    int* rowptr = (int*)(ws_f + 2 * N128);   // NN+1
    int* cur = rowptr + NN + 1;              // NN
    int* esrc = cur + NN;                    // EE
    int* bsum = esrc + EE;                   // nbN

    const int nbN = (NN + 255) / 256;  // 391
    const int nbE = (EE + 255) / 256;  // 3125
    const int nbG = (NN + 63) / 64;    // 1563
    const int nbW = (NN + 3) / 4;      // 4 waves/block

    // CSR by destination
    k_init<<<nbN, 256, 0, stream>>>(cur);
    k_hist<<<nbE, 256, 0, stream>>>(ei, cur);
    k_scanA<<<nbN, 256, 0, stream>>>(cur, bsum);
    k_scanB<<<1, 64, 0, stream>>>(bsum, rowptr, nbN);
    k_scanC<<<nbN, 256, 0, stream>>>(cur, rowptr, bsum);
    k_scat<<<nbE, 256, 0, stream>>>(ei, cur, esrc);

    // layer 1: g = h1 + bias1
    k_gemm2<<<nbG, 256, 0, stream>>>(x, Wl1, bl1, Wr1, br1, xl, xr);
    k_edge1<0><<<nbW, 256, 0, stream>>>(xl, xr, rowptr, esrc, att1, bias1, out);
    // layer 2: g += h2 + bias2
    k_gemm2<<<nbG, 256, 0, stream>>>(x, Wl2, bl2, Wr2, br2, xl, xr);
    k_edge1<1><<<nbW, 256, 0, stream>>>(xl, xr, rowptr, esrc, att2, bias2, out);

    // out = [g | temb] @ Wc.T + bc   (reads+overwrites d_out, row-disjoint per block)
    k_final<<<nbG, 256, 0, stream>>>(out, nt, Wt, bt, Wc, bc, out);
}

// Round 10
// 796.437 us; speedup vs baseline: 1.1200x; 1.1200x over previous
//
#include <hip/hip_runtime.h>
#include <math.h>

#define NN 100000
#define EE 800000
static constexpr size_t N128 = (size_t)NN * 128;

__device__ __forceinline__ float lrelu(float x) { return x >= 0.f ? x : 0.2f * x; }

// ---------------- init: zero degree counters ----------------
__global__ void k_init(int* __restrict__ deg) {
    int i = blockIdx.x * blockDim.x + threadIdx.x;
    if (i < NN) deg[i] = 0;
}

// ---------------- histogram of dst (edge_index arrives as int32) ----------------
__global__ void k_hist(const int* __restrict__ ei, int* __restrict__ deg) {
    int e = blockIdx.x * blockDim.x + threadIdx.x;
    if (e < EE) {
        int dst = ei[EE + e];
        atomicAdd(&deg[dst], 1);
    }
}

// ---------------- scan pass A: per-block sums ----------------
__global__ void k_scanA(const int* __restrict__ deg, int* __restrict__ bsum) {
    int b = blockIdx.x, t = threadIdx.x;
    int i = b * 256 + t;
    int v = (i < NN) ? deg[i] : 0;
    #pragma unroll
    for (int d = 1; d < 64; d <<= 1) v += __shfl_xor(v, d);
    __shared__ int ws[4];
    int lane = t & 63, w = t >> 6;
    if (lane == 0) ws[w] = v;
    __syncthreads();
    if (t == 0) bsum[b] = ws[0] + ws[1] + ws[2] + ws[3];
}

// ---------------- scan pass B: exclusive scan of block sums (1 wave) ----------------
__global__ void k_scanB(int* __restrict__ bsum, int* __restrict__ rowptr, int nb) {
    int lane = threadIdx.x;
    int carry = 0;
    for (int base = 0; base < nb; base += 64) {
        int i = base + lane;
        int v = (i < nb) ? bsum[i] : 0;
        int incl = v;
        #pragma unroll
        for (int d = 1; d < 64; d <<= 1) {
            int u = __shfl_up(incl, d);
            if (lane >= d) incl += u;
        }
        if (i < nb) bsum[i] = carry + incl - v;  // exclusive offset
        carry += __shfl(incl, 63);
    }
    if (lane == 0) rowptr[NN] = carry;  // == EE
}

// ---------------- scan pass C: in-block exclusive scan -> rowptr, cursor ----------------
__global__ void k_scanC(int* __restrict__ deg_and_cur, int* __restrict__ rowptr,
                        const int* __restrict__ bsum) {
    int b = blockIdx.x, t = threadIdx.x;
    int i = b * 256 + t;
    int lane = t & 63, w = t >> 6;
    int v = (i < NN) ? deg_and_cur[i] : 0;
    int incl = v;
    #pragma unroll
    for (int d = 1; d < 64; d <<= 1) {
        int u = __shfl_up(incl, d);
        if (lane >= d) incl += u;
    }
    __shared__ int wtot[4];
    if (lane == 63) wtot[w] = incl;
    __syncthreads();
    int woff = 0;
    for (int k = 0; k < w; k++) woff += wtot[k];
    int excl = woff + incl - v + bsum[b];
    if (i < NN) {
        rowptr[i] = excl;
        deg_and_cur[i] = excl;  // cursor copy for scatter
    }
}

// ---------------- scatter edges into CSR (store src only) ----------------
__global__ void k_scat(const int* __restrict__ ei, int* __restrict__ cur,
                       int* __restrict__ esrc) {
    int e = blockIdx.x * blockDim.x + threadIdx.x;
    if (e < EE) {
        int src = ei[e];
        int dst = ei[EE + e];
        int pos = atomicAdd(&cur[dst], 1);
        esrc[pos] = src;
    }
}

// ---------------- per-layer transform GEMM: xl, xr ----------------
// o_m[n][c] = sum_k x[n][k] * W_m[c][k] + b_m[c]
// v3 (R9 counters: conflicts 1.52e7 unchanged after xs removal -> they live in
// wsm; occupancy flat -> barrier-latency-bound):
//  - wsmT[m][kk][129]: transposed W staging; b-reads are 16 lanes x contiguous
//    16B (2-way bank aliasing = free), killing the row-stride conflicts.
//  - m-loop merged into one k-pass: halves a-loads and barriers (8->4),
//    FMA:load ratio 256:20 per kk.
__global__ __launch_bounds__(256) void k_gemm2(
    const float* __restrict__ x,
    const float* __restrict__ W0, const float* __restrict__ B0,
    const float* __restrict__ W1, const float* __restrict__ B1,
    float* __restrict__ o0, float* __restrict__ o1) {
    __shared__ float4 wsmT[2][8][129];   // [matrix][kk][col], 33 KB
    int tid = threadIdx.x;
    int row0 = blockIdx.x * 64;
    int ty = tid >> 4, tx = tid & 15;

    int grow[4], gclamp[4];
    #pragma unroll
    for (int i = 0; i < 4; i++) {
        grow[i] = row0 + ty + 16 * i;
        gclamp[i] = grow[i] < NN ? grow[i] : NN - 1;
    }
    const float4* x4 = (const float4*)x;
    const float4* Wm4[2] = {(const float4*)W0, (const float4*)W1};

    float acc0[4][8], acc1[4][8];
    #pragma unroll
    for (int i = 0; i < 4; i++)
        #pragma unroll
        for (int j = 0; j < 8; j++) { acc0[i][j] = 0.f; acc1[i][j] = 0.f; }

    for (int kc = 0; kc < 4; kc++) {
        __syncthreads();  // protect wsmT from previous chunk's readers
        // stage both W chunks, transposed: 2048 float4s, 8 per thread
        #pragma unroll
        for (int q = 0; q < 8; q++) {
            int mm = q >> 2;                 // 0,0,0,0,1,1,1,1 (static)
            int rem = (q & 3) * 256 + tid;   // 0..1023
            int r = rem >> 3, c4 = rem & 7;
            wsmT[mm][c4][r] = Wm4[mm][r * 32 + kc * 8 + c4];
        }
        __syncthreads();
        #pragma unroll
        for (int kk = 0; kk < 8; kk++) {
            float4 a[4];
            #pragma unroll
            for (int i = 0; i < 4; i++)
                a[i] = x4[(size_t)gclamp[i] * 32 + kc * 8 + kk];
            // matrix 0
            {
                float4 b[8];
                #pragma unroll
                for (int j = 0; j < 8; j++) b[j] = wsmT[0][kk][tx + 16 * j];
                #pragma unroll
                for (int i = 0; i < 4; i++)
                    #pragma unroll
                    for (int j = 0; j < 8; j++) {
                        acc0[i][j] += a[i].x * b[j].x;
                        acc0[i][j] += a[i].y * b[j].y;
                        acc0[i][j] += a[i].z * b[j].z;
                        acc0[i][j] += a[i].w * b[j].w;
                    }
            }
            // matrix 1
            {
                float4 b[8];
                #pragma unroll
                for (int j = 0; j < 8; j++) b[j] = wsmT[1][kk][tx + 16 * j];
                #pragma unroll
                for (int i = 0; i < 4; i++)
                    #pragma unroll
                    for (int j = 0; j < 8; j++) {
                        acc1[i][j] += a[i].x * b[j].x;
                        acc1[i][j] += a[i].y * b[j].y;
                        acc1[i][j] += a[i].z * b[j].z;
                        acc1[i][j] += a[i].w * b[j].w;
                    }
            }
        }
    }
    #pragma unroll
    for (int i = 0; i < 4; i++) {
        if (grow[i] < NN) {
            #pragma unroll
            for (int j = 0; j < 8; j++) {
                int c = tx + 16 * j;
                o0[(size_t)grow[i] * 128 + c] = acc0[i][j] + B0[c];
                o1[(size_t)grow[i] * 128 + c] = acc1[i][j] + B1[c];
            }
        }
    }
}

// ---------------- edge phase (one layer): one wave per destination node ----------------
// ACC=0: g[dst] = h + bias      ACC=1: g[dst] += h + bias
template <int ACC>
__global__ __launch_bounds__(256) void k_edge1(
    const float* __restrict__ xl, const float* __restrict__ xr,
    const int* __restrict__ rowptr, const int* __restrict__ esrc,
    const float* __restrict__ att, const float* __restrict__ bias,
    float* __restrict__ g) {
    int wid = (blockIdx.x * blockDim.x + threadIdx.x) >> 6;
    if (wid >= NN) return;
    int lane = threadIdx.x & 63;
    int c0 = 2 * lane;         // global channel of .x
    int h = lane >> 4;         // head
    int ch = c0 & 31;          // in-head channel

    float2 xrv = *(const float2*)(xr + (size_t)wid * 128 + c0);
    float2 a = *(const float2*)(att + h * 32 + ch);

    int beg = rowptr[wid], end = rowptr[wid + 1];
    float s = 0.f, acc0 = 0.f, acc1 = 0.f;

    for (int e = beg; e < end; ++e) {
        int src = esrc[e];  // uniform across wave (broadcast)
        float2 v = *(const float2*)(xl + (size_t)src * 128 + c0);
        float t = lrelu(v.x + xrv.x) * a.x + lrelu(v.y + xrv.y) * a.y;
        // 16-lane (per-head) sum
        #pragma unroll
        for (int d = 1; d < 16; d <<= 1) t += __shfl_xor(t, d);
        // softmax without max-subtraction: logits are O(+-10), exp is safe,
        // and the max cancels mathematically in ex/sum(ex)
        float ex = __expf(t);
        s += ex;
        acc0 += ex * v.x;
        acc1 += ex * v.y;
    }
    float r = s > 0.f ? 1.f / (s + 1e-16f) : 0.f;
    float2 gv;
    gv.x = acc0 * r + bias[c0];
    gv.y = acc1 * r + bias[c0 + 1];
    float2* gp = (float2*)(g + (size_t)wid * 128 + c0);
    if (ACC) {
        float2 old = *gp;
        gv.x += old.x;
        gv.y += old.y;
    }
    *gp = gv;
}

// ---------------- final projection: out = [g128 | temb(nt)] @ Wc.T + bc ----------------
// temb computed on the fly; g128 lives in d_out and is overwritten (row-disjoint per block)
__global__ __launch_bounds__(256) void k_final(
    const float* __restrict__ g128, const float* __restrict__ nt,
    const float* __restrict__ Wt, const float* __restrict__ bt,
    const float* __restrict__ Wc, const float* __restrict__ bc,
    float* __restrict__ out) {
    __shared__ float4 gs[64][41];   // 40 float4 = 160 floats per row
    __shared__ float4 wc[128][9];
    int tid = threadIdx.x;
    int row0 = blockIdx.x * 64;
    #pragma unroll
    for (int q = 0; q < 8; q++) {
        int idx = q * 256 + tid;
        int r = idx >> 5, c4 = idx & 31;
        int gr = row0 + r;
        float4 v = {0.f, 0.f, 0.f, 0.f};
        if (gr < NN) v = ((const float4*)g128)[(size_t)gr * 32 + c4];
        gs[r][c4] = v;
    }
    // type-embedding part: 64 rows x 8 float4 (32 channels), computed on the fly
    #pragma unroll
    for (int q = 0; q < 2; q++) {
        int idx = q * 256 + tid;
        int r = idx >> 3, c4 = idx & 7;
        int gr = row0 + r;
        float4 v = {0.f, 0.f, 0.f, 0.f};
        if (gr < NN) {
            float n0 = nt[2 * gr], n1 = nt[2 * gr + 1];
            #pragma unroll
            for (int u = 0; u < 4; u++) {
                int c = c4 * 4 + u;
                ((float*)&v)[u] = n0 * Wt[2 * c] + n1 * Wt[2 * c + 1] + bt[c];
            }
        }
        gs[r][32 + c4] = v;
    }
    int ty = tid >> 4, tx = tid & 15;
    float acc[4][8];
    #pragma unroll
    for (int i = 0; i < 4; i++)
        #pragma unroll
        for (int j = 0; j < 8; j++) acc[i][j] = 0.f;

    for (int kc = 0; kc < 5; kc++) {
        __syncthreads();
        #pragma unroll
        for (int q = 0; q < 4; q++) {
            int idx = q * 256 + tid;
            int r = idx >> 3, c4 = idx & 7;
            wc[r][c4] = ((const float4*)Wc)[r * 40 + kc * 8 + c4];
        }
        __syncthreads();
        #pragma unroll
        for (int kk = 0; kk < 8; kk++) {
            float4 a[4], b[8];
            #pragma unroll
            for (int i = 0; i < 4; i++) a[i] = gs[ty + 16 * i][kc * 8 + kk];
            #pragma unroll
            for (int j = 0; j < 8; j++) b[j] = wc[tx + 16 * j][kk];
            #pragma unroll
            for (int i = 0; i < 4; i++)
                #pragma unroll
                for (int j = 0; j < 8; j++) {
                    acc[i][j] += a[i].x * b[j].x;
                    acc[i][j] += a[i].y * b[j].y;
                    acc[i][j] += a[i].z * b[j].z;
                    acc[i][j] += a[i].w * b[j].w;
                }
        }
    }
    #pragma unroll
    for (int i = 0; i < 4; i++) {
        int gr = row0 + ty + 16 * i;
        if (gr < NN) {
            #pragma unroll
            for (int j = 0; j < 8; j++) {
                int c = tx + 16 * j;
                out[(size_t)gr * 128 + c] = acc[i][j] + bc[c];
            }
        }
    }
}

extern "C" void kernel_launch(void* const* d_in, const int* in_sizes, int n_in,
                              void* d_out, int out_size, void* d_ws, size_t ws_size,
                              hipStream_t stream) {
    const float* x = (const float*)d_in[0];
    const int* ei = (const int*)d_in[1];    // harness converts int64 -> int32
    const float* nt = (const float*)d_in[2];
    const float* Wl1 = (const float*)d_in[3];
    const float* bl1 = (const float*)d_in[4];
    const float* Wr1 = (const float*)d_in[5];
    const float* br1 = (const float*)d_in[6];
    const float* att1 = (const float*)d_in[7];
    const float* bias1 = (const float*)d_in[8];
    const float* Wl2 = (const float*)d_in[9];
    const float* bl2 = (const float*)d_in[10];
    const float* Wr2 = (const float*)d_in[11];
    const float* br2 = (const float*)d_in[12];
    const float* att2 = (const float*)d_in[13];
    const float* bias2 = (const float*)d_in[14];
    const float* Wt = (const float*)d_in[15];
    const float* bt = (const float*)d_in[16];
    const float* Wc = (const float*)d_in[17];
    const float* bc = (const float*)d_in[18];
    float* out = (float*)d_out;

    // workspace layout (~107 MB): xl, xr (reused across the two layer passes) + CSR ints.
    // The accumulated g128 = h1+h2 lives in d_out.
    float* ws_f = (float*)d_ws;
    float* xl = ws_f;
    float* xr = ws_f + N128;
    int* rowptr = (int*)(ws_f + 2 * N128);   // NN+1
    int* cur = rowptr + NN + 1;              // NN
    int* esrc = cur + NN;                    // EE
    int* bsum = esrc + EE;                   // nbN

    const int nbN = (NN + 255) / 256;  // 391
    const int nbE = (EE + 255) / 256;  // 3125
    const int nbG = (NN + 63) / 64;    // 1563
    const int nbW = (NN + 3) / 4;      // 4 waves/block

    // CSR by destination
    k_init<<<nbN, 256, 0, stream>>>(cur);
    k_hist<<<nbE, 256, 0, stream>>>(ei, cur);
    k_scanA<<<nbN, 256, 0, stream>>>(cur, bsum);
    k_scanB<<<1, 64, 0, stream>>>(bsum, rowptr, nbN);
    k_scanC<<<nbN, 256, 0, stream>>>(cur, rowptr, bsum);
    k_scat<<<nbE, 256, 0, stream>>>(ei, cur, esrc);

    // layer 1: g = h1 + bias1
    k_gemm2<<<nbG, 256, 0, stream>>>(x, Wl1, bl1, Wr1, br1, xl, xr);
    k_edge1<0><<<nbW, 256, 0, stream>>>(xl, xr, rowptr, esrc, att1, bias1, out);
    // layer 2: g += h2 + bias2
    k_gemm2<<<nbG, 256, 0, stream>>>(x, Wl2, bl2, Wr2, br2, xl, xr);
    k_edge1<1><<<nbW, 256, 0, stream>>>(xl, xr, rowptr, esrc, att2, bias2, out);

    // out = [g | temb] @ Wc.T + bc   (reads+overwrites d_out, row-disjoint per block)
    k_final<<<nbG, 256, 0, stream>>>(out, nt, Wt, bt, Wc, bc, out);
}